// Round 6
// baseline (179.728 us; speedup 1.0000x reference)
//
#include <hip/hip_runtime.h>
#include <hip/hip_bf16.h>
#include <math.h>

// ---------------- problem constants ----------------
#define N_ROWS 65536
#define H 256
#define DOUT 64
#define NC 4
#define NLAYERS_HIDDEN 3
#define DIN_PE 84
#define KPE 96          // padded K for layer 0 (84 -> 96, zeros)
#define XE_STRIDE 104   // padded LDS row stride for xe
#define BM 64           // rows per block
#define FB_STRIDE 68    // fp32 out-staging row stride

// fragment-ordered weight chunk: one (kstep, nblk) pair = 64 lanes x 8 bf16
#define CHUNK 512
#define WT0_PER_E (3 * 16 * CHUNK)      // 24576
#define WTH_PER_L (8 * 16 * CHUNK)      // 65536
#define WTOUT_PER_E (8 * 4 * CHUNK)     // 16384

using bf16 = __hip_bfloat16;
typedef __bf16 bf16x8 __attribute__((ext_vector_type(8)));
typedef float f32x4 __attribute__((ext_vector_type(4)));

// ---------------- bucket rows by expert ----------------
__global__ void bucket_kernel(const int* __restrict__ layer_id,
                              int* __restrict__ gcnt, int* __restrict__ idx) {
  __shared__ int lcnt[NC];
  __shared__ int lbase[NC];
  const int tid = threadIdx.x;
  if (tid < NC) lcnt[tid] = 0;
  __syncthreads();
  const int i = blockIdx.x * blockDim.x + tid;
  const int e = layer_id[i];
  const int lp = atomicAdd(&lcnt[e], 1);
  __syncthreads();
  if (tid < NC) lbase[tid] = atomicAdd(&gcnt[tid], lcnt[tid]);
  __syncthreads();
  idx[e * N_ROWS + lbase[e] + lp] = i;
}

// ---------------- fp32 -> bf16 fragment-ordered weights ----------------
// element [lane*8 + j] of chunk (kbi,nblk) holds W^T[n][k] with
// n = nblk*16 + (lane&15), k = kbi*32 + (lane>>4)*8 + j.
__global__ void prep_weights(const float* __restrict__ W0,
                             const float* __restrict__ Wh,
                             const float* __restrict__ Wout,
                             bf16* __restrict__ wt0, bf16* __restrict__ wth,
                             bf16* __restrict__ wtout) {
  const int n0 = NC * WT0_PER_E;
  const int nh = NC * 3 * WTH_PER_L;
  const int no = NC * WTOUT_PER_E;
  const int total = n0 + nh + no;
  for (int i = blockIdx.x * blockDim.x + threadIdx.x; i < total;
       i += gridDim.x * blockDim.x) {
    if (i < n0) {
      int c = i / WT0_PER_E; int r = i % WT0_PER_E;
      int kbi = r / (16 * CHUNK); int r2 = r % (16 * CHUNK);
      int nblk = r2 / CHUNK; int w = r2 % CHUNK;
      int lane = w / 8, j = w % 8;
      int n = nblk * 16 + (lane & 15);
      int k = kbi * 32 + (lane >> 4) * 8 + j;
      float v = (k < DIN_PE) ? W0[(c * DIN_PE + k) * H + n] : 0.f;
      wt0[i] = __float2bfloat16(v);
    } else if (i < n0 + nh) {
      int u = i - n0;
      int cl = u / WTH_PER_L; int r = u % WTH_PER_L;   // cl = c*3 + l
      int kbi = r / (16 * CHUNK); int r2 = r % (16 * CHUNK);
      int nblk = r2 / CHUNK; int w = r2 % CHUNK;
      int lane = w / 8, j = w % 8;
      int n = nblk * 16 + (lane & 15);
      int k = kbi * 32 + (lane >> 4) * 8 + j;
      wth[u] = __float2bfloat16(Wh[(cl * H + k) * H + n]);
    } else {
      int u = i - n0 - nh;
      int c = u / WTOUT_PER_E; int r = u % WTOUT_PER_E;
      int kbi = r / (4 * CHUNK); int r2 = r % (4 * CHUNK);
      int nblk = r2 / CHUNK; int w = r2 % CHUNK;
      int lane = w / 8, j = w % 8;
      int n = nblk * 16 + (lane & 15);
      int k = kbi * 32 + (lane >> 4) * 8 + j;
      wtout[u] = __float2bfloat16(Wout[(c * H + k) * DOUT + n]);
    }
  }
}

// ---------------- main fused MLP (rolled, compact 1D grid) ----------------
// Every launched block does real work: block bid maps to (expert, tile) via
// ceil-div scan of gcnt. 4 blocks/CU resident (VGPR<=128, LDS 33.3KB).
__global__ __launch_bounds__(256, 4) void mlp_kernel(
    const float* __restrict__ x, const float* __restrict__ in_dim,
    const int* __restrict__ gcnt, const int* __restrict__ idx,
    const bf16* __restrict__ wt0, const float* __restrict__ b0,
    const bf16* __restrict__ wth, const float* __restrict__ bh,
    const float* __restrict__ scal, const bf16* __restrict__ wtout,
    const float* __restrict__ bout, float* __restrict__ out) {
  const int bid = blockIdx.x;
  const int c0 = gcnt[0], c1 = gcnt[1], c2 = gcnt[2], c3 = gcnt[3];
  const int n0 = (c0 + 63) >> 6, n1 = (c1 + 63) >> 6, n2 = (c2 + 63) >> 6,
            n3 = (c3 + 63) >> 6;
  int e, tb, cnt;
  if (bid < n0) { e = 0; tb = bid; cnt = c0; }
  else if (bid < n0 + n1) { e = 1; tb = bid - n0; cnt = c1; }
  else if (bid < n0 + n1 + n2) { e = 2; tb = bid - n0 - n1; cnt = c2; }
  else if (bid < n0 + n1 + n2 + n3) { e = 3; tb = bid - n0 - n1 - n2; cnt = c3; }
  else return;
  const int base = tb * BM;

  __shared__ int ridx[BM];
  __shared__ float indim_s[BM];
  // overlays: xe [64][104] bf16 (13312B) -> hbuf [64][256] bf16 swizzled
  // (32768B) -> fbuf [64][68] f32 (17408B). Barrier-protected transitions.
  __shared__ __align__(16) char smem[BM * H * 2];
  bf16* xe = (bf16*)smem;
  bf16* hbuf = (bf16*)smem;
  float* fbuf = (float*)smem;

  const int tid = threadIdx.x;
  if (tid < BM) {
    int p = base + tid;
    int ri = (p < cnt) ? idx[e * N_ROWS + p] : -1;
    ridx[tid] = ri;
    indim_s[tid] = (ri >= 0) ? in_dim[ri] : 1.f;
  }
  __syncthreads();

  // ---- positional encoding: 4 threads per row ----
  {
    const int r = tid >> 2, d = tid & 3;
    const int ri = ridx[r];
    float xd = 0.f, x3 = 1.f;
    if (ri >= 0) { xd = x[ri * 4 + d]; x3 = x[ri * 4 + 3]; }
    float v = (d < 3) ? (xd / x3) : x3;
    if (ri < 0) v = 0.f;
    bf16* row = xe + r * XE_STRIDE;
    row[d] = __float2bfloat16(v);
    float f = 3.14159265358979323846f;
#pragma unroll 1
    for (int q = 0; q < 10; ++q) {
      float sn, cs;
      __sincosf(v * f, &sn, &cs);
      row[4 + q * 8 + d * 2] = __float2bfloat16(sn);
      row[4 + q * 8 + d * 2 + 1] = __float2bfloat16(cs);
      f *= 2.f;
    }
#pragma unroll 1
    for (int c = DIN_PE + d; c < XE_STRIDE; c += 4) row[c] = __float2bfloat16(0.f);
  }
  __syncthreads();

  const int lane = tid & 63;
  const int wid = tid >> 6;
  const int l15 = lane & 15;
  const int lq = lane >> 4;
  const int wb = wid * 64;  // this wave's column base

  f32x4 acc[4][4];

  // ---- layer 0: xe[64xKPE] @ wt0^T -> h ----
  {
    const bf16* W = wt0 + (size_t)e * WT0_PER_E + lane * 8;
    const float* bias = b0 + e * H;
#pragma unroll
    for (int nt = 0; nt < 4; ++nt) {
      float b = bias[wb + nt * 16 + l15];
      f32x4 bv = {b, b, b, b};
#pragma unroll
      for (int mt = 0; mt < 4; ++mt) acc[mt][nt] = bv;
    }
#pragma unroll 1
    for (int kb = 0; kb < 3; ++kb) {  // kstep index (K = 3*32)
      bf16x8 a[4], bw[4];
#pragma unroll
      for (int nt = 0; nt < 4; ++nt)
        bw[nt] = *(const bf16x8*)(W + (kb * 16 + wid * 4 + nt) * CHUNK);
#pragma unroll
      for (int mt = 0; mt < 4; ++mt) {
        int row = mt * 16 + l15;
        a[mt] = *(const bf16x8*)(xe + row * XE_STRIDE + kb * 32 + lq * 8);
      }
#pragma unroll
      for (int mt = 0; mt < 4; ++mt)
#pragma unroll
        for (int nt = 0; nt < 4; ++nt)
          acc[mt][nt] = __builtin_amdgcn_mfma_f32_16x16x32_bf16(
              a[mt], bw[nt], acc[mt][nt], 0, 0, 0);
    }
    __syncthreads();  // all waves done reading xe before hbuf overwrites it
    // epilogue: relu -> swizzled LDS write (no residual at layer 0)
#pragma unroll
    for (int mt = 0; mt < 4; ++mt)
#pragma unroll
      for (int nt = 0; nt < 4; ++nt) {
        int col = wb + nt * 16 + l15;
#pragma unroll
        for (int j = 0; j < 4; ++j) {
          int row = mt * 16 + lq * 4 + j;
          float hv = fmaxf(acc[mt][nt][j], 0.f);
          int byte = (row * H + col) * 2;
          byte ^= ((row & 7) << 4);
          *(bf16*)((char*)hbuf + byte) = __float2bfloat16(hv);
        }
      }
  }
  __syncthreads();

  // ---- hidden residual layers (rolled; unroll-2 ping-pong B prefetch) ----
#pragma unroll 1
  for (int l = 0; l < NLAYERS_HIDDEN; ++l) {
    const bf16* W = wth + (size_t)(e * 3 + l) * WTH_PER_L + lane * 8;
    const float* bias = bh + (e * 3 + l) * H;
    const float sc = scal[e * 3 + l];
#pragma unroll
    for (int nt = 0; nt < 4; ++nt) {
      float b = bias[wb + nt * 16 + l15];
      f32x4 bv = {b, b, b, b};
#pragma unroll
      for (int mt = 0; mt < 4; ++mt) acc[mt][nt] = bv;
    }
    bf16x8 bw0[4], bw1[4];
#pragma unroll
    for (int nt = 0; nt < 4; ++nt)
      bw0[nt] = *(const bf16x8*)(W + (wid * 4 + nt) * CHUNK);
#pragma unroll 1
    for (int kb = 0; kb < 8; kb += 2) {
      // half A: prefetch bw1 <- kb+1, compute with bw0 (kb)
#pragma unroll
      for (int nt = 0; nt < 4; ++nt)
        bw1[nt] = *(const bf16x8*)(W + ((kb + 1) * 16 + wid * 4 + nt) * CHUNK);
      {
        bf16x8 a[4];
#pragma unroll
        for (int mt = 0; mt < 4; ++mt) {
          int row = mt * 16 + l15;
          int byte = (row * H + kb * 32 + lq * 8) * 2;
          byte ^= ((row & 7) << 4);
          a[mt] = *(const bf16x8*)((const char*)hbuf + byte);
        }
#pragma unroll
        for (int mt = 0; mt < 4; ++mt)
#pragma unroll
          for (int nt = 0; nt < 4; ++nt)
            acc[mt][nt] = __builtin_amdgcn_mfma_f32_16x16x32_bf16(
                a[mt], bw0[nt], acc[mt][nt], 0, 0, 0);
      }
      // half B: prefetch bw0 <- kb+2 (wraps harmlessly at end), compute bw1
      {
        int kn = (kb + 2) & 7;
#pragma unroll
        for (int nt = 0; nt < 4; ++nt)
          bw0[nt] = *(const bf16x8*)(W + (kn * 16 + wid * 4 + nt) * CHUNK);
        bf16x8 a[4];
#pragma unroll
        for (int mt = 0; mt < 4; ++mt) {
          int row = mt * 16 + l15;
          int byte = (row * H + (kb + 1) * 32 + lq * 8) * 2;
          byte ^= ((row & 7) << 4);
          a[mt] = *(const bf16x8*)((const char*)hbuf + byte);
        }
#pragma unroll
        for (int mt = 0; mt < 4; ++mt)
#pragma unroll
          for (int nt = 0; nt < 4; ++nt)
            acc[mt][nt] = __builtin_amdgcn_mfma_f32_16x16x32_bf16(
                a[mt], bw1[nt], acc[mt][nt], 0, 0, 0);
      }
    }
    __syncthreads();  // all waves done READING hbuf before overwrite
#pragma unroll
    for (int mt = 0; mt < 4; ++mt)
#pragma unroll
      for (int nt = 0; nt < 4; ++nt) {
        int col = wb + nt * 16 + l15;
#pragma unroll
        for (int j = 0; j < 4; ++j) {
          int row = mt * 16 + lq * 4 + j;
          int byte = (row * H + col) * 2;
          byte ^= ((row & 7) << 4);
          bf16* p = (bf16*)((char*)hbuf + byte);
          float hp = __bfloat162float(*p);  // residual: same-thread RMW
          float hv = sc * fmaxf(acc[mt][nt][j], 0.f) + hp;
          *p = __float2bfloat16(hv);
        }
      }
    __syncthreads();
  }

  // ---- output layer: h[64xH] @ wtout^T -> fbuf fp32 (ping-pong B) ----
  {
    const bf16* W = wtout + (size_t)e * WTOUT_PER_E + lane * 8;
    const float* bias = bout + e * DOUT;
    f32x4 facc[4];
#pragma unroll
    for (int nt = 0; nt < 4; ++nt) {
      float b = bias[nt * 16 + l15];
      f32x4 bv = {b, b, b, b};
      facc[nt] = bv;
    }
    const int arow = wid * 16 + l15;  // wave w owns output rows [16w,16w+16)
    bf16x8 bw0[4], bw1[4];
#pragma unroll
    for (int nt = 0; nt < 4; ++nt)
      bw0[nt] = *(const bf16x8*)(W + nt * CHUNK);
#pragma unroll 1
    for (int kb = 0; kb < 8; kb += 2) {
#pragma unroll
      for (int nt = 0; nt < 4; ++nt)
        bw1[nt] = *(const bf16x8*)(W + ((kb + 1) * 4 + nt) * CHUNK);
      {
        int byte = (arow * H + kb * 32 + lq * 8) * 2;
        byte ^= ((arow & 7) << 4);
        bf16x8 a = *(const bf16x8*)((const char*)hbuf + byte);
#pragma unroll
        for (int nt = 0; nt < 4; ++nt)
          facc[nt] = __builtin_amdgcn_mfma_f32_16x16x32_bf16(a, bw0[nt], facc[nt], 0, 0, 0);
      }
      {
        int kn = (kb + 2) & 7;
#pragma unroll
        for (int nt = 0; nt < 4; ++nt)
          bw0[nt] = *(const bf16x8*)(W + (kn * 4 + nt) * CHUNK);
        int byte = (arow * H + (kb + 1) * 32 + lq * 8) * 2;
        byte ^= ((arow & 7) << 4);
        bf16x8 a = *(const bf16x8*)((const char*)hbuf + byte);
#pragma unroll
        for (int nt = 0; nt < 4; ++nt)
          facc[nt] = __builtin_amdgcn_mfma_f32_16x16x32_bf16(a, bw1[nt], facc[nt], 0, 0, 0);
      }
    }
    __syncthreads();  // hbuf dead; fbuf overlays it
#pragma unroll
    for (int nt = 0; nt < 4; ++nt) {
      int col = nt * 16 + l15;
#pragma unroll
      for (int j = 0; j < 4; ++j) {
        int row = wid * 16 + lq * 4 + j;
        fbuf[row * FB_STRIDE + col] = facc[nt][j];
      }
    }
  }
  __syncthreads();

  // ---- coalesced scatter: full 256B rows via float4 lanes ----
#pragma unroll 1
  for (int p = 0; p < 4; ++p) {
    int item = p * 256 + tid;
    int row = item >> 4;
    int ch = item & 15;
    int ri = ridx[row];
    if (ri >= 0) {
      f32x4 v = *(const f32x4*)(fbuf + row * FB_STRIDE + ch * 4);
      float inv = indim_s[row];
      v[0] /= inv; v[1] /= inv; v[2] /= inv; v[3] /= inv;
      *(f32x4*)(out + (size_t)ri * DOUT + ch * 4) = v;
    }
  }
}

// ---------------- launch ----------------
extern "C" void kernel_launch(void* const* d_in, const int* in_sizes, int n_in,
                              void* d_out, int out_size, void* d_ws,
                              size_t ws_size, hipStream_t stream) {
  const float* x = (const float*)d_in[0];
  const float* in_dim = (const float*)d_in[1];
  const int* layer_id = (const int*)d_in[2];
  const float* W0 = (const float*)d_in[3];
  const float* b0 = (const float*)d_in[4];
  const float* Wh = (const float*)d_in[5];
  const float* bh = (const float*)d_in[6];
  const float* scal = (const float*)d_in[7];
  const float* Wout = (const float*)d_in[8];
  const float* bout = (const float*)d_in[9];
  float* out = (float*)d_out;

  char* ws = (char*)d_ws;
  int* gcnt = (int*)ws;                                  // 16 B
  int* idx = (int*)(ws + 16);                            // NC*N_ROWS*4 = 1 MB
  bf16* wt0 = (bf16*)(ws + 16 + (size_t)NC * N_ROWS * 4);
  bf16* wth = wt0 + NC * WT0_PER_E;
  bf16* wtout = wth + NC * 3 * WTH_PER_L;

  hipMemsetAsync(gcnt, 0, NC * sizeof(int), stream);
  bucket_kernel<<<N_ROWS / 256, 256, 0, stream>>>(layer_id, gcnt, idx);
  prep_weights<<<512, 256, 0, stream>>>(W0, Wh, Wout, wt0, wth, wtout);
  // compact grid: exactly enough blocks to cover all experts (+NC-1 rounding)
  mlp_kernel<<<N_ROWS / BM + NC - 1, 256, 0, stream>>>(
      x, in_dim, gcnt, idx, wt0, b0, wth, bh, scal, wtout, bout, out);
}

// Round 7
// 149.954 us; speedup vs baseline: 1.1986x; 1.1986x over previous
//
#include <hip/hip_runtime.h>
#include <hip/hip_bf16.h>
#include <math.h>

// ---------------- problem constants ----------------
#define N_ROWS 65536
#define H 256
#define DOUT 64
#define NC 4
#define NLAYERS_HIDDEN 3
#define DIN_PE 84
#define KPE 96          // padded K for layer 0 (84 -> 96, zeros)
#define XE_STRIDE 104   // padded LDS row stride for xe
#define BM 64           // rows per block
#define FB_STRIDE 68    // fp32 out-staging row stride

// fragment-ordered weight chunk: one (kstep, nblk) pair = 64 lanes x 8 bf16
#define CHUNK 512
#define WT0_PER_E (3 * 16 * CHUNK)      // 24576
#define WTH_PER_L (8 * 16 * CHUNK)      // 65536
#define WTOUT_PER_E (8 * 4 * CHUNK)     // 16384

using bf16 = __hip_bfloat16;
typedef __bf16 bf16x8 __attribute__((ext_vector_type(8)));
typedef float f32x4 __attribute__((ext_vector_type(4)));

// ---------------- bucket rows by expert ----------------
__global__ void bucket_kernel(const int* __restrict__ layer_id,
                              int* __restrict__ gcnt, int* __restrict__ idx) {
  __shared__ int lcnt[NC];
  __shared__ int lbase[NC];
  const int tid = threadIdx.x;
  if (tid < NC) lcnt[tid] = 0;
  __syncthreads();
  const int i = blockIdx.x * blockDim.x + tid;
  const int e = layer_id[i];
  const int lp = atomicAdd(&lcnt[e], 1);
  __syncthreads();
  if (tid < NC) lbase[tid] = atomicAdd(&gcnt[tid], lcnt[tid]);
  __syncthreads();
  idx[e * N_ROWS + lbase[e] + lp] = i;
}

// ---------------- fp32 -> bf16 fragment-ordered weights ----------------
// element [lane*8 + j] of chunk (kbi,nblk) holds W^T[n][k] with
// n = nblk*16 + (lane&15), k = kbi*32 + (lane>>4)*8 + j.
__global__ void prep_weights(const float* __restrict__ W0,
                             const float* __restrict__ Wh,
                             const float* __restrict__ Wout,
                             bf16* __restrict__ wt0, bf16* __restrict__ wth,
                             bf16* __restrict__ wtout) {
  const int n0 = NC * WT0_PER_E;
  const int nh = NC * 3 * WTH_PER_L;
  const int no = NC * WTOUT_PER_E;
  const int total = n0 + nh + no;
  for (int i = blockIdx.x * blockDim.x + threadIdx.x; i < total;
       i += gridDim.x * blockDim.x) {
    if (i < n0) {
      int c = i / WT0_PER_E; int r = i % WT0_PER_E;
      int kbi = r / (16 * CHUNK); int r2 = r % (16 * CHUNK);
      int nblk = r2 / CHUNK; int w = r2 % CHUNK;
      int lane = w / 8, j = w % 8;
      int n = nblk * 16 + (lane & 15);
      int k = kbi * 32 + (lane >> 4) * 8 + j;
      float v = (k < DIN_PE) ? W0[(c * DIN_PE + k) * H + n] : 0.f;
      wt0[i] = __float2bfloat16(v);
    } else if (i < n0 + nh) {
      int u = i - n0;
      int cl = u / WTH_PER_L; int r = u % WTH_PER_L;   // cl = c*3 + l
      int kbi = r / (16 * CHUNK); int r2 = r % (16 * CHUNK);
      int nblk = r2 / CHUNK; int w = r2 % CHUNK;
      int lane = w / 8, j = w % 8;
      int n = nblk * 16 + (lane & 15);
      int k = kbi * 32 + (lane >> 4) * 8 + j;
      wth[u] = __float2bfloat16(Wh[(cl * H + k) * H + n]);
    } else {
      int u = i - n0 - nh;
      int c = u / WTOUT_PER_E; int r = u % WTOUT_PER_E;
      int kbi = r / (4 * CHUNK); int r2 = r % (4 * CHUNK);
      int nblk = r2 / CHUNK; int w = r2 % CHUNK;
      int lane = w / 8, j = w % 8;
      int n = nblk * 16 + (lane & 15);
      int k = kbi * 32 + (lane >> 4) * 8 + j;
      wtout[u] = __float2bfloat16(Wout[(c * H + k) * DOUT + n]);
    }
  }
}

// ---------------- main fused MLP (rolled, compact 1D grid) ----------------
// Every launched block does real work: block bid maps to (expert, tile) via
// ceil-div scan of gcnt. Residency is LDS-limited (33.3KB -> 4 blocks/CU);
// launch_bounds min-waves=3 keeps VGPR at ~84 (NO SPILLS -- the recurring
// regression: bounds=4 squeezes to 64 VGPR and spills, see R3/R6).
__global__ __launch_bounds__(256, 3) void mlp_kernel(
    const float* __restrict__ x, const float* __restrict__ in_dim,
    const int* __restrict__ gcnt, const int* __restrict__ idx,
    const bf16* __restrict__ wt0, const float* __restrict__ b0,
    const bf16* __restrict__ wth, const float* __restrict__ bh,
    const float* __restrict__ scal, const bf16* __restrict__ wtout,
    const float* __restrict__ bout, float* __restrict__ out) {
  const int bid = blockIdx.x;
  const int c0 = gcnt[0], c1 = gcnt[1], c2 = gcnt[2], c3 = gcnt[3];
  const int n0 = (c0 + 63) >> 6, n1 = (c1 + 63) >> 6, n2 = (c2 + 63) >> 6,
            n3 = (c3 + 63) >> 6;
  int e, tb, cnt;
  if (bid < n0) { e = 0; tb = bid; cnt = c0; }
  else if (bid < n0 + n1) { e = 1; tb = bid - n0; cnt = c1; }
  else if (bid < n0 + n1 + n2) { e = 2; tb = bid - n0 - n1; cnt = c2; }
  else if (bid < n0 + n1 + n2 + n3) { e = 3; tb = bid - n0 - n1 - n2; cnt = c3; }
  else return;
  const int base = tb * BM;

  __shared__ int ridx[BM];
  __shared__ float indim_s[BM];
  // overlays: xe [64][104] bf16 (13312B) -> hbuf [64][256] bf16 swizzled
  // (32768B) -> fbuf [64][68] f32 (17408B). Barrier-protected transitions.
  __shared__ __align__(16) char smem[BM * H * 2];
  bf16* xe = (bf16*)smem;
  bf16* hbuf = (bf16*)smem;
  float* fbuf = (float*)smem;

  const int tid = threadIdx.x;
  if (tid < BM) {
    int p = base + tid;
    int ri = (p < cnt) ? idx[e * N_ROWS + p] : -1;
    ridx[tid] = ri;
    indim_s[tid] = (ri >= 0) ? in_dim[ri] : 1.f;
  }
  __syncthreads();

  // ---- positional encoding: 4 threads per row ----
  {
    const int r = tid >> 2, d = tid & 3;
    const int ri = ridx[r];
    float xd = 0.f, x3 = 1.f;
    if (ri >= 0) { xd = x[ri * 4 + d]; x3 = x[ri * 4 + 3]; }
    float v = (d < 3) ? (xd / x3) : x3;
    if (ri < 0) v = 0.f;
    bf16* row = xe + r * XE_STRIDE;
    row[d] = __float2bfloat16(v);
    float f = 3.14159265358979323846f;
#pragma unroll 1
    for (int q = 0; q < 10; ++q) {
      float sn, cs;
      __sincosf(v * f, &sn, &cs);
      row[4 + q * 8 + d * 2] = __float2bfloat16(sn);
      row[4 + q * 8 + d * 2 + 1] = __float2bfloat16(cs);
      f *= 2.f;
    }
#pragma unroll 1
    for (int c = DIN_PE + d; c < XE_STRIDE; c += 4) row[c] = __float2bfloat16(0.f);
  }
  __syncthreads();

  const int lane = tid & 63;
  const int wid = tid >> 6;
  const int l15 = lane & 15;
  const int lq = lane >> 4;
  const int wb = wid * 64;  // this wave's column base

  f32x4 acc[4][4];

  // ---- layer 0: xe[64xKPE] @ wt0^T -> h ----
  {
    const bf16* W = wt0 + (size_t)e * WT0_PER_E + lane * 8;
    const float* bias = b0 + e * H;
#pragma unroll
    for (int nt = 0; nt < 4; ++nt) {
      float b = bias[wb + nt * 16 + l15];
      f32x4 bv = {b, b, b, b};
#pragma unroll
      for (int mt = 0; mt < 4; ++mt) acc[mt][nt] = bv;
    }
#pragma unroll 1
    for (int kb = 0; kb < 3; ++kb) {  // kstep index (K = 3*32)
      bf16x8 a[4], bw[4];
#pragma unroll
      for (int nt = 0; nt < 4; ++nt)
        bw[nt] = *(const bf16x8*)(W + (kb * 16 + wid * 4 + nt) * CHUNK);
#pragma unroll
      for (int mt = 0; mt < 4; ++mt) {
        int row = mt * 16 + l15;
        a[mt] = *(const bf16x8*)(xe + row * XE_STRIDE + kb * 32 + lq * 8);
      }
#pragma unroll
      for (int mt = 0; mt < 4; ++mt)
#pragma unroll
        for (int nt = 0; nt < 4; ++nt)
          acc[mt][nt] = __builtin_amdgcn_mfma_f32_16x16x32_bf16(
              a[mt], bw[nt], acc[mt][nt], 0, 0, 0);
    }
    __syncthreads();  // all waves done reading xe before hbuf overwrites it
    // epilogue: relu -> swizzled LDS write (no residual at layer 0)
#pragma unroll
    for (int mt = 0; mt < 4; ++mt)
#pragma unroll
      for (int nt = 0; nt < 4; ++nt) {
        int col = wb + nt * 16 + l15;
#pragma unroll
        for (int j = 0; j < 4; ++j) {
          int row = mt * 16 + lq * 4 + j;
          float hv = fmaxf(acc[mt][nt][j], 0.f);
          int byte = (row * H + col) * 2;
          byte ^= ((row & 7) << 4);
          *(bf16*)((char*)hbuf + byte) = __float2bfloat16(hv);
        }
      }
  }
  __syncthreads();

  // ---- hidden residual layers (rolled; unroll-2 ping-pong B prefetch) ----
#pragma unroll 1
  for (int l = 0; l < NLAYERS_HIDDEN; ++l) {
    const bf16* W = wth + (size_t)(e * 3 + l) * WTH_PER_L + lane * 8;
    const float* bias = bh + (e * 3 + l) * H;
    const float sc = scal[e * 3 + l];
#pragma unroll
    for (int nt = 0; nt < 4; ++nt) {
      float b = bias[wb + nt * 16 + l15];
      f32x4 bv = {b, b, b, b};
#pragma unroll
      for (int mt = 0; mt < 4; ++mt) acc[mt][nt] = bv;
    }
    bf16x8 bw0[4], bw1[4];
#pragma unroll
    for (int nt = 0; nt < 4; ++nt)
      bw0[nt] = *(const bf16x8*)(W + (wid * 4 + nt) * CHUNK);
#pragma unroll 1
    for (int kb = 0; kb < 8; kb += 2) {
      // half A: prefetch bw1 <- kb+1, compute with bw0 (kb)
#pragma unroll
      for (int nt = 0; nt < 4; ++nt)
        bw1[nt] = *(const bf16x8*)(W + ((kb + 1) * 16 + wid * 4 + nt) * CHUNK);
      {
        bf16x8 a[4];
#pragma unroll
        for (int mt = 0; mt < 4; ++mt) {
          int row = mt * 16 + l15;
          int byte = (row * H + kb * 32 + lq * 8) * 2;
          byte ^= ((row & 7) << 4);
          a[mt] = *(const bf16x8*)((const char*)hbuf + byte);
        }
#pragma unroll
        for (int mt = 0; mt < 4; ++mt)
#pragma unroll
          for (int nt = 0; nt < 4; ++nt)
            acc[mt][nt] = __builtin_amdgcn_mfma_f32_16x16x32_bf16(
                a[mt], bw0[nt], acc[mt][nt], 0, 0, 0);
      }
      // half B: prefetch bw0 <- kb+2 (wraps harmlessly at end), compute bw1
      {
        int kn = (kb + 2) & 7;
#pragma unroll
        for (int nt = 0; nt < 4; ++nt)
          bw0[nt] = *(const bf16x8*)(W + (kn * 16 + wid * 4 + nt) * CHUNK);
        bf16x8 a[4];
#pragma unroll
        for (int mt = 0; mt < 4; ++mt) {
          int row = mt * 16 + l15;
          int byte = (row * H + (kb + 1) * 32 + lq * 8) * 2;
          byte ^= ((row & 7) << 4);
          a[mt] = *(const bf16x8*)((const char*)hbuf + byte);
        }
#pragma unroll
        for (int mt = 0; mt < 4; ++mt)
#pragma unroll
          for (int nt = 0; nt < 4; ++nt)
            acc[mt][nt] = __builtin_amdgcn_mfma_f32_16x16x32_bf16(
                a[mt], bw1[nt], acc[mt][nt], 0, 0, 0);
      }
    }
    __syncthreads();  // all waves done READING hbuf before overwrite
#pragma unroll
    for (int mt = 0; mt < 4; ++mt)
#pragma unroll
      for (int nt = 0; nt < 4; ++nt) {
        int col = wb + nt * 16 + l15;
#pragma unroll
        for (int j = 0; j < 4; ++j) {
          int row = mt * 16 + lq * 4 + j;
          int byte = (row * H + col) * 2;
          byte ^= ((row & 7) << 4);
          bf16* p = (bf16*)((char*)hbuf + byte);
          float hp = __bfloat162float(*p);  // residual: same-thread RMW
          float hv = sc * fmaxf(acc[mt][nt][j], 0.f) + hp;
          *p = __float2bfloat16(hv);
        }
      }
    __syncthreads();
  }

  // ---- output layer: h[64xH] @ wtout^T -> fbuf fp32 (ping-pong B) ----
  {
    const bf16* W = wtout + (size_t)e * WTOUT_PER_E + lane * 8;
    const float* bias = bout + e * DOUT;
    f32x4 facc[4];
#pragma unroll
    for (int nt = 0; nt < 4; ++nt) {
      float b = bias[nt * 16 + l15];
      f32x4 bv = {b, b, b, b};
      facc[nt] = bv;
    }
    const int arow = wid * 16 + l15;  // wave w owns output rows [16w,16w+16)
    bf16x8 bw0[4], bw1[4];
#pragma unroll
    for (int nt = 0; nt < 4; ++nt)
      bw0[nt] = *(const bf16x8*)(W + nt * CHUNK);
#pragma unroll 1
    for (int kb = 0; kb < 8; kb += 2) {
#pragma unroll
      for (int nt = 0; nt < 4; ++nt)
        bw1[nt] = *(const bf16x8*)(W + ((kb + 1) * 4 + nt) * CHUNK);
      {
        int byte = (arow * H + kb * 32 + lq * 8) * 2;
        byte ^= ((arow & 7) << 4);
        bf16x8 a = *(const bf16x8*)((const char*)hbuf + byte);
#pragma unroll
        for (int nt = 0; nt < 4; ++nt)
          facc[nt] = __builtin_amdgcn_mfma_f32_16x16x32_bf16(a, bw0[nt], facc[nt], 0, 0, 0);
      }
      {
        int kn = (kb + 2) & 7;
#pragma unroll
        for (int nt = 0; nt < 4; ++nt)
          bw0[nt] = *(const bf16x8*)(W + (kn * 4 + nt) * CHUNK);
        int byte = (arow * H + (kb + 1) * 32 + lq * 8) * 2;
        byte ^= ((arow & 7) << 4);
        bf16x8 a = *(const bf16x8*)((const char*)hbuf + byte);
#pragma unroll
        for (int nt = 0; nt < 4; ++nt)
          facc[nt] = __builtin_amdgcn_mfma_f32_16x16x32_bf16(a, bw1[nt], facc[nt], 0, 0, 0);
      }
    }
    __syncthreads();  // hbuf dead; fbuf overlays it
#pragma unroll
    for (int nt = 0; nt < 4; ++nt) {
      int col = nt * 16 + l15;
#pragma unroll
      for (int j = 0; j < 4; ++j) {
        int row = wid * 16 + lq * 4 + j;
        fbuf[row * FB_STRIDE + col] = facc[nt][j];
      }
    }
  }
  __syncthreads();

  // ---- coalesced scatter: full 256B rows via float4 lanes ----
#pragma unroll 1
  for (int p = 0; p < 4; ++p) {
    int item = p * 256 + tid;
    int row = item >> 4;
    int ch = item & 15;
    int ri = ridx[row];
    if (ri >= 0) {
      f32x4 v = *(const f32x4*)(fbuf + row * FB_STRIDE + ch * 4);
      float inv = indim_s[row];
      v[0] /= inv; v[1] /= inv; v[2] /= inv; v[3] /= inv;
      *(f32x4*)(out + (size_t)ri * DOUT + ch * 4) = v;
    }
  }
}

// ---------------- launch ----------------
extern "C" void kernel_launch(void* const* d_in, const int* in_sizes, int n_in,
                              void* d_out, int out_size, void* d_ws,
                              size_t ws_size, hipStream_t stream) {
  const float* x = (const float*)d_in[0];
  const float* in_dim = (const float*)d_in[1];
  const int* layer_id = (const int*)d_in[2];
  const float* W0 = (const float*)d_in[3];
  const float* b0 = (const float*)d_in[4];
  const float* Wh = (const float*)d_in[5];
  const float* bh = (const float*)d_in[6];
  const float* scal = (const float*)d_in[7];
  const float* Wout = (const float*)d_in[8];
  const float* bout = (const float*)d_in[9];
  float* out = (float*)d_out;

  char* ws = (char*)d_ws;
  int* gcnt = (int*)ws;                                  // 16 B
  int* idx = (int*)(ws + 16);                            // NC*N_ROWS*4 = 1 MB
  bf16* wt0 = (bf16*)(ws + 16 + (size_t)NC * N_ROWS * 4);
  bf16* wth = wt0 + NC * WT0_PER_E;
  bf16* wtout = wth + NC * 3 * WTH_PER_L;

  hipMemsetAsync(gcnt, 0, NC * sizeof(int), stream);
  bucket_kernel<<<N_ROWS / 256, 256, 0, stream>>>(layer_id, gcnt, idx);
  prep_weights<<<512, 256, 0, stream>>>(W0, Wh, Wout, wt0, wth, wtout);
  // compact grid: exactly enough blocks to cover all experts (+NC-1 rounding)
  mlp_kernel<<<N_ROWS / BM + NC - 1, 256, 0, stream>>>(
      x, in_dim, gcnt, idx, wt0, b0, wth, bh, scal, wtout, bout, out);
}

// Round 8
// 144.643 us; speedup vs baseline: 1.2426x; 1.0367x over previous
//
#include <hip/hip_runtime.h>
#include <hip/hip_bf16.h>
#include <math.h>

// ---------------- problem constants ----------------
#define N_ROWS 65536
#define H 256
#define DOUT 64
#define NC 4
#define NLAYERS_HIDDEN 3
#define DIN_PE 84
#define KPE 96          // padded K for layer 0 (84 -> 96, zeros)
#define XE_STRIDE 104   // padded LDS row stride for xe
#define BM 64           // rows per block
#define FB_STRIDE 68    // fp32 out-staging row stride

// fragment-ordered weight chunk: one (kstep, nblk) pair = 64 lanes x 8 bf16
#define CHUNK 512
#define WT0_PER_E (3 * 16 * CHUNK)      // 24576
#define WTH_PER_L (8 * 16 * CHUNK)      // 65536
#define WTOUT_PER_E (8 * 4 * CHUNK)     // 16384

using bf16 = __hip_bfloat16;
typedef __bf16 bf16x8 __attribute__((ext_vector_type(8)));
typedef float f32x4 __attribute__((ext_vector_type(4)));

// ---------------- bucket rows by expert ----------------
__global__ void bucket_kernel(const int* __restrict__ layer_id,
                              int* __restrict__ gcnt, int* __restrict__ idx) {
  __shared__ int lcnt[NC];
  __shared__ int lbase[NC];
  const int tid = threadIdx.x;
  if (tid < NC) lcnt[tid] = 0;
  __syncthreads();
  const int i = blockIdx.x * blockDim.x + tid;
  const int e = layer_id[i];
  const int lp = atomicAdd(&lcnt[e], 1);
  __syncthreads();
  if (tid < NC) lbase[tid] = atomicAdd(&gcnt[tid], lcnt[tid]);
  __syncthreads();
  idx[e * N_ROWS + lbase[e] + lp] = i;
}

// ---------------- fp32 -> bf16 fragment-ordered weights ----------------
// element [lane*8 + j] of chunk (kbi,nblk) holds W^T[n][k] with
// n = nblk*16 + (lane&15), k = kbi*32 + (lane>>4)*8 + j.
// This is exactly the MFMA A-fragment layout for A = W^T (row i=n, k-major).
__global__ void prep_weights(const float* __restrict__ W0,
                             const float* __restrict__ Wh,
                             const float* __restrict__ Wout,
                             bf16* __restrict__ wt0, bf16* __restrict__ wth,
                             bf16* __restrict__ wtout) {
  const int n0 = NC * WT0_PER_E;
  const int nh = NC * 3 * WTH_PER_L;
  const int no = NC * WTOUT_PER_E;
  const int total = n0 + nh + no;
  for (int i = blockIdx.x * blockDim.x + threadIdx.x; i < total;
       i += gridDim.x * blockDim.x) {
    if (i < n0) {
      int c = i / WT0_PER_E; int r = i % WT0_PER_E;
      int kbi = r / (16 * CHUNK); int r2 = r % (16 * CHUNK);
      int nblk = r2 / CHUNK; int w = r2 % CHUNK;
      int lane = w / 8, j = w % 8;
      int n = nblk * 16 + (lane & 15);
      int k = kbi * 32 + (lane >> 4) * 8 + j;
      float v = (k < DIN_PE) ? W0[(c * DIN_PE + k) * H + n] : 0.f;
      wt0[i] = __float2bfloat16(v);
    } else if (i < n0 + nh) {
      int u = i - n0;
      int cl = u / WTH_PER_L; int r = u % WTH_PER_L;   // cl = c*3 + l
      int kbi = r / (16 * CHUNK); int r2 = r % (16 * CHUNK);
      int nblk = r2 / CHUNK; int w = r2 % CHUNK;
      int lane = w / 8, j = w % 8;
      int n = nblk * 16 + (lane & 15);
      int k = kbi * 32 + (lane >> 4) * 8 + j;
      wth[u] = __float2bfloat16(Wh[(cl * H + k) * H + n]);
    } else {
      int u = i - n0 - nh;
      int c = u / WTOUT_PER_E; int r = u % WTOUT_PER_E;
      int kbi = r / (4 * CHUNK); int r2 = r % (4 * CHUNK);
      int nblk = r2 / CHUNK; int w = r2 % CHUNK;
      int lane = w / 8, j = w % 8;
      int n = nblk * 16 + (lane & 15);
      int k = kbi * 32 + (lane >> 4) * 8 + j;
      wtout[u] = __float2bfloat16(Wout[(c * H + k) * DOUT + n]);
    }
  }
}

// ---------------- main fused MLP (swapped-operand MFMA) ----------------
// Every layer computed TRANSPOSED: h'^T = (W^T)(h^T). A-frag = weight
// (fragment-ordered global), B-frag = activation hs[m][n] (swizzled b128
// read: lane holds m=l15 fixed, 8 consecutive n). D-layout: lane holds
// m=l15 fixed, 4 CONSECUTIVE n' -> epilogue is one b64 RMW per tile
// (16 LDS ops/layer vs 128 scalar). Same wt arrays, same grid.
__global__ __launch_bounds__(256, 3) void mlp_kernel(
    const float* __restrict__ x, const float* __restrict__ in_dim,
    const int* __restrict__ gcnt, const int* __restrict__ idx,
    const bf16* __restrict__ wt0, const float* __restrict__ b0,
    const bf16* __restrict__ wth, const float* __restrict__ bh,
    const float* __restrict__ scal, const bf16* __restrict__ wtout,
    const float* __restrict__ bout, float* __restrict__ out) {
  const int bid = blockIdx.x;
  const int c0 = gcnt[0], c1 = gcnt[1], c2 = gcnt[2], c3 = gcnt[3];
  const int n0 = (c0 + 63) >> 6, n1 = (c1 + 63) >> 6, n2 = (c2 + 63) >> 6,
            n3 = (c3 + 63) >> 6;
  int e, tb, cnt;
  if (bid < n0) { e = 0; tb = bid; cnt = c0; }
  else if (bid < n0 + n1) { e = 1; tb = bid - n0; cnt = c1; }
  else if (bid < n0 + n1 + n2) { e = 2; tb = bid - n0 - n1; cnt = c2; }
  else if (bid < n0 + n1 + n2 + n3) { e = 3; tb = bid - n0 - n1 - n2; cnt = c3; }
  else return;
  const int base = tb * BM;

  __shared__ int ridx[BM];
  __shared__ float indim_s[BM];
  // overlays: xe [64][104] bf16 (13312B) -> hs [64 m][256 n] bf16 swizzled
  // (32768B) -> fbuf [64][68] f32 (17408B). Barrier-protected transitions.
  __shared__ __align__(16) char smem[BM * H * 2];
  bf16* xe = (bf16*)smem;
  bf16* hs = (bf16*)smem;
  float* fbuf = (float*)smem;

  const int tid = threadIdx.x;
  if (tid < BM) {
    int p = base + tid;
    int ri = (p < cnt) ? idx[e * N_ROWS + p] : -1;
    ridx[tid] = ri;
    indim_s[tid] = (ri >= 0) ? in_dim[ri] : 1.f;
  }
  __syncthreads();

  // ---- positional encoding: 4 threads per row ----
  {
    const int r = tid >> 2, d = tid & 3;
    const int ri = ridx[r];
    float xd = 0.f, x3 = 1.f;
    if (ri >= 0) { xd = x[ri * 4 + d]; x3 = x[ri * 4 + 3]; }
    float v = (d < 3) ? (xd / x3) : x3;
    if (ri < 0) v = 0.f;
    bf16* row = xe + r * XE_STRIDE;
    row[d] = __float2bfloat16(v);
    float f = 3.14159265358979323846f;
#pragma unroll 1
    for (int q = 0; q < 10; ++q) {
      float sn, cs;
      __sincosf(v * f, &sn, &cs);
      row[4 + q * 8 + d * 2] = __float2bfloat16(sn);
      row[4 + q * 8 + d * 2 + 1] = __float2bfloat16(cs);
      f *= 2.f;
    }
#pragma unroll 1
    for (int c = DIN_PE + d; c < XE_STRIDE; c += 4) row[c] = __float2bfloat16(0.f);
  }
  __syncthreads();

  const int lane = tid & 63;
  const int wid = tid >> 6;
  const int l15 = lane & 15;
  const int lq = lane >> 4;
  const int wb = wid * 64;  // this wave's n' (hidden-out) base

  f32x4 acc[4][4];  // [it = n'-tile][jt = m-tile]

  // ---- layer 0: h1^T = (W0^T)(xe^T), B-frag from row-major xe ----
  {
    const bf16* W = wt0 + (size_t)e * WT0_PER_E + lane * 8;
    const float* bias = b0 + e * H + wb;
#pragma unroll
    for (int it = 0; it < 4; ++it) {
      f32x4 bv = *(const f32x4*)(bias + it * 16 + lq * 4);
#pragma unroll
      for (int jt = 0; jt < 4; ++jt) acc[it][jt] = bv;
    }
#pragma unroll 1
    for (int kb = 0; kb < 3; ++kb) {  // kstep index (K = 3*32)
      bf16x8 aw[4], bx[4];
#pragma unroll
      for (int it = 0; it < 4; ++it)
        aw[it] = *(const bf16x8*)(W + (kb * 16 + wid * 4 + it) * CHUNK);
#pragma unroll
      for (int jt = 0; jt < 4; ++jt)
        bx[jt] = *(const bf16x8*)(xe + (jt * 16 + l15) * XE_STRIDE + kb * 32 + lq * 8);
#pragma unroll
      for (int it = 0; it < 4; ++it)
#pragma unroll
        for (int jt = 0; jt < 4; ++jt)
          acc[it][jt] = __builtin_amdgcn_mfma_f32_16x16x32_bf16(
              aw[it], bx[jt], acc[it][jt], 0, 0, 0);
    }
    __syncthreads();  // all waves done reading xe before hs overwrites it
    // epilogue: relu -> b64 write per tile (lane: m=l15 fixed, 4 consec n')
#pragma unroll
    for (int it = 0; it < 4; ++it)
#pragma unroll
      for (int jt = 0; jt < 4; ++jt) {
        int m = jt * 16 + l15;
        int nb = wb + it * 16 + lq * 4;
        int byte = ((m * H + nb) * 2) ^ ((l15 & 7) << 4);
        bf16 neu[4];
#pragma unroll
        for (int r = 0; r < 4; ++r)
          neu[r] = __float2bfloat16(fmaxf(acc[it][jt][r], 0.f));
        *(ushort4*)((char*)hs + byte) = *(ushort4*)neu;
      }
  }
  __syncthreads();

  // ---- hidden residual layers (rolled; ping-pong weight prefetch) ----
#pragma unroll 1
  for (int l = 0; l < NLAYERS_HIDDEN; ++l) {
    const bf16* W = wth + (size_t)(e * 3 + l) * WTH_PER_L + lane * 8;
    const float* bias = bh + (e * 3 + l) * H + wb;
    const float sc = scal[e * 3 + l];
#pragma unroll
    for (int it = 0; it < 4; ++it) {
      f32x4 bv = *(const f32x4*)(bias + it * 16 + lq * 4);
#pragma unroll
      for (int jt = 0; jt < 4; ++jt) acc[it][jt] = bv;
    }
    bf16x8 aw0[4], aw1[4];
#pragma unroll
    for (int it = 0; it < 4; ++it)
      aw0[it] = *(const bf16x8*)(W + (wid * 4 + it) * CHUNK);
#pragma unroll 1
    for (int kb = 0; kb < 8; kb += 2) {
      // half A: prefetch aw1 <- kb+1, compute with aw0 (kb)
#pragma unroll
      for (int it = 0; it < 4; ++it)
        aw1[it] = *(const bf16x8*)(W + ((kb + 1) * 16 + wid * 4 + it) * CHUNK);
      {
        bf16x8 bx[4];
#pragma unroll
        for (int jt = 0; jt < 4; ++jt) {
          int m = jt * 16 + l15;
          int byte = ((m * H + kb * 32 + lq * 8) * 2) ^ ((l15 & 7) << 4);
          bx[jt] = *(const bf16x8*)((const char*)hs + byte);
        }
#pragma unroll
        for (int it = 0; it < 4; ++it)
#pragma unroll
          for (int jt = 0; jt < 4; ++jt)
            acc[it][jt] = __builtin_amdgcn_mfma_f32_16x16x32_bf16(
                aw0[it], bx[jt], acc[it][jt], 0, 0, 0);
      }
      // half B: prefetch aw0 <- kb+2 (wraps harmlessly), compute aw1
      {
        int kn = (kb + 2) & 7;
#pragma unroll
        for (int it = 0; it < 4; ++it)
          aw0[it] = *(const bf16x8*)(W + (kn * 16 + wid * 4 + it) * CHUNK);
        bf16x8 bx[4];
#pragma unroll
        for (int jt = 0; jt < 4; ++jt) {
          int m = jt * 16 + l15;
          int byte = ((m * H + (kb + 1) * 32 + lq * 8) * 2) ^ ((l15 & 7) << 4);
          bx[jt] = *(const bf16x8*)((const char*)hs + byte);
        }
#pragma unroll
        for (int it = 0; it < 4; ++it)
#pragma unroll
          for (int jt = 0; jt < 4; ++jt)
            acc[it][jt] = __builtin_amdgcn_mfma_f32_16x16x32_bf16(
                aw1[it], bx[jt], acc[it][jt], 0, 0, 0);
      }
    }
    __syncthreads();  // all waves done READING hs before overwrite
    // epilogue: b64 RMW per tile (residual = same-thread previous write)
#pragma unroll
    for (int it = 0; it < 4; ++it)
#pragma unroll
      for (int jt = 0; jt < 4; ++jt) {
        int m = jt * 16 + l15;
        int nb = wb + it * 16 + lq * 4;
        int byte = ((m * H + nb) * 2) ^ ((l15 & 7) << 4);
        ushort4* p = (ushort4*)((char*)hs + byte);
        bf16 old[4]; *(ushort4*)old = *p;
        bf16 neu[4];
#pragma unroll
        for (int r = 0; r < 4; ++r) {
          float hv = sc * fmaxf(acc[it][jt][r], 0.f) + __bfloat162float(old[r]);
          neu[r] = __float2bfloat16(hv);
        }
        *p = *(ushort4*)neu;
      }
    __syncthreads();
  }

  // ---- output layer: out^T = (Wout^T)(h^T) -> fbuf[m][o] fp32 ----
  {
    const bf16* W = wtout + (size_t)e * WTOUT_PER_E + lane * 8;
    const float* bias = bout + e * DOUT + wid * 16;
    f32x4 facc[4];
    f32x4 bv = *(const f32x4*)(bias + lq * 4);
#pragma unroll
    for (int jt = 0; jt < 4; ++jt) facc[jt] = bv;
    bf16x8 aw0, aw1;
    aw0 = *(const bf16x8*)(W + wid * CHUNK);
#pragma unroll 1
    for (int kb = 0; kb < 8; kb += 2) {
      aw1 = *(const bf16x8*)(W + ((kb + 1) * 4 + wid) * CHUNK);
      {
        bf16x8 bx[4];
#pragma unroll
        for (int jt = 0; jt < 4; ++jt) {
          int m = jt * 16 + l15;
          int byte = ((m * H + kb * 32 + lq * 8) * 2) ^ ((l15 & 7) << 4);
          bx[jt] = *(const bf16x8*)((const char*)hs + byte);
        }
#pragma unroll
        for (int jt = 0; jt < 4; ++jt)
          facc[jt] = __builtin_amdgcn_mfma_f32_16x16x32_bf16(aw0, bx[jt], facc[jt], 0, 0, 0);
      }
      {
        int kn = (kb + 2) & 7;
        aw0 = *(const bf16x8*)(W + (kn * 4 + wid) * CHUNK);
        bf16x8 bx[4];
#pragma unroll
        for (int jt = 0; jt < 4; ++jt) {
          int m = jt * 16 + l15;
          int byte = ((m * H + (kb + 1) * 32 + lq * 8) * 2) ^ ((l15 & 7) << 4);
          bx[jt] = *(const bf16x8*)((const char*)hs + byte);
        }
#pragma unroll
        for (int jt = 0; jt < 4; ++jt)
          facc[jt] = __builtin_amdgcn_mfma_f32_16x16x32_bf16(aw1, bx[jt], facc[jt], 0, 0, 0);
      }
    }
    __syncthreads();  // hs dead; fbuf overlays it
    // lane holds (m = jt*16+l15, o = wid*16 + lq*4 + r): f32x4 store per jt
#pragma unroll
    for (int jt = 0; jt < 4; ++jt) {
      int m = jt * 16 + l15;
      *(f32x4*)(fbuf + m * FB_STRIDE + wid * 16 + lq * 4) = facc[jt];
    }
  }
  __syncthreads();

  // ---- coalesced scatter: full 256B rows via float4 lanes ----
#pragma unroll 1
  for (int p = 0; p < 4; ++p) {
    int item = p * 256 + tid;
    int row = item >> 4;
    int ch = item & 15;
    int ri = ridx[row];
    if (ri >= 0) {
      f32x4 v = *(const f32x4*)(fbuf + row * FB_STRIDE + ch * 4);
      float inv = indim_s[row];
      v[0] /= inv; v[1] /= inv; v[2] /= inv; v[3] /= inv;
      *(f32x4*)(out + (size_t)ri * DOUT + ch * 4) = v;
    }
  }
}

// ---------------- launch ----------------
extern "C" void kernel_launch(void* const* d_in, const int* in_sizes, int n_in,
                              void* d_out, int out_size, void* d_ws,
                              size_t ws_size, hipStream_t stream) {
  const float* x = (const float*)d_in[0];
  const float* in_dim = (const float*)d_in[1];
  const int* layer_id = (const int*)d_in[2];
  const float* W0 = (const float*)d_in[3];
  const float* b0 = (const float*)d_in[4];
  const float* Wh = (const float*)d_in[5];
  const float* bh = (const float*)d_in[6];
  const float* scal = (const float*)d_in[7];
  const float* Wout = (const float*)d_in[8];
  const float* bout = (const float*)d_in[9];
  float* out = (float*)d_out;

  char* ws = (char*)d_ws;
  int* gcnt = (int*)ws;                                  // 16 B
  int* idx = (int*)(ws + 16);                            // NC*N_ROWS*4 = 1 MB
  bf16* wt0 = (bf16*)(ws + 16 + (size_t)NC * N_ROWS * 4);
  bf16* wth = wt0 + NC * WT0_PER_E;
  bf16* wtout = wth + NC * 3 * WTH_PER_L;

  hipMemsetAsync(gcnt, 0, NC * sizeof(int), stream);
  bucket_kernel<<<N_ROWS / 256, 256, 0, stream>>>(layer_id, gcnt, idx);
  prep_weights<<<512, 256, 0, stream>>>(W0, Wh, Wout, wt0, wth, wtout);
  // compact grid: exactly enough blocks to cover all experts (+NC-1 rounding)
  mlp_kernel<<<N_ROWS / BM + NC - 1, 256, 0, stream>>>(
      x, in_dim, gcnt, idx, wt0, b0, wth, bh, scal, wtout, bout, out);
}